// Round 5
// baseline (305.013 us; speedup 1.0000x reference)
//
#include <hip/hip_runtime.h>
#include <hip/hip_bf16.h>
#include <math.h>

using short8 = __attribute__((ext_vector_type(8))) short;   // 8 bf16 (4 VGPR)
using f32x4  = __attribute__((ext_vector_type(4))) float;   // MFMA acc

#define MFMA16(a, b, c) __builtin_amdgcn_mfma_f32_16x16x32_bf16(a, b, c, 0, 0, 0)

__device__ __forceinline__ short f2bs(float f) {
    __hip_bfloat16 h = __float2bfloat16(f);          // RNE
    return __builtin_bit_cast(short, h);
}
__device__ __forceinline__ float bs2f(short s) {
    return __uint_as_float(((unsigned)(unsigned short)s) << 16);
}

// ---------------- prep kernels ----------------

__global__ void k_cvt(const float* __restrict__ in, short* __restrict__ out, int n4) {
    int i = blockIdx.x * 256 + threadIdx.x;
    if (i >= n4) return;
    float4 v = *(const float4*)(in + i * 4);
    out[i * 4 + 0] = f2bs(v.x); out[i * 4 + 1] = f2bs(v.y);
    out[i * 4 + 2] = f2bs(v.z); out[i * 4 + 3] = f2bs(v.w);
}

// w2 [64][32][4][4] -> Wc2 [oc][kh*128 + kw*32 + ic]
__global__ void k_prep_wc2(const float* __restrict__ w, short* __restrict__ o) {
    int i = blockIdx.x * 256 + threadIdx.x;
    if (i >= 32768) return;
    int oc = i >> 9, col = i & 511;
    int kh = col >> 7, kw = (col >> 5) & 3, ic = col & 31;
    o[i] = f2bs(w[((oc * 32 + ic) * 4 + kh) * 4 + kw]);
}

// w3 [64][64][3][3] -> Wc3 [oc][kh*192 + kw*64 + ic]
__global__ void k_prep_wc3(const float* __restrict__ w, short* __restrict__ o) {
    int i = blockIdx.x * 256 + threadIdx.x;
    if (i >= 36864) return;
    int oc = i / 576, col = i % 576;
    int kh = col / 192, r = col % 192, kw = r >> 6, ic = r & 63;
    o[i] = f2bs(w[((oc * 64 + ic) * 3 + kh) * 3 + kw]);
}

// fcW [512][11264] (K = oc*176+pix) -> fcWr [512][pix*64+oc] via LDS transpose, 1 row/block
__global__ void k_prep_fcw2(const float* __restrict__ w, short* __restrict__ o) {
    __shared__ short t[176 * 76];
    int r = blockIdx.x, tid = threadIdx.x;
    for (int it = 0; it < 11; ++it) {
        int c4 = it * 256 + tid;                 // 2816 float4s exactly
        float4 v = *(const float4*)(w + (size_t)r * 11264 + c4 * 4);
        int c = c4 * 4;
        int oc = c / 176, pix = c % 176;         // 4 consecutive pix share oc (176%4==0)
        t[(pix + 0) * 76 + oc] = f2bs(v.x);
        t[(pix + 1) * 76 + oc] = f2bs(v.y);
        t[(pix + 2) * 76 + oc] = f2bs(v.z);
        t[(pix + 3) * 76 + oc] = f2bs(v.w);
    }
    __syncthreads();
    for (int it = 0; it < 6; ++it) {
        int j8 = it * 256 + tid;
        if (j8 < 1408) {
            int j = j8 * 8, pix = j >> 6, oc0 = j & 63;
            const short* tp = &t[pix * 76 + oc0];
            short8 v;
            ((uint2*)&v)[0] = *(const uint2*)tp;
            ((uint2*)&v)[1] = *(const uint2*)(tp + 4);
            *(short8*)&o[(size_t)r * 11264 + j] = v;
        }
    }
}

__global__ void k_prep_hm(const float* __restrict__ h0, const int* __restrict__ done,
                          short* __restrict__ hm) {
    int i = blockIdx.x * 256 + threadIdx.x;
    if (i < 16384) {
        float m = 1.f - (float)done[i >> 9];
        hm[i] = f2bs(h0[i] * m);
    }
}

__global__ void k_bias2(const float* __restrict__ a, const float* __restrict__ b,
                        float* __restrict__ o) {
    int i = blockIdx.x * 256 + threadIdx.x;
    if (i < 2048) o[i] = a[i] + b[i];
}

// concat two 512-float bias vectors
__global__ void k_cat2(const float* __restrict__ a, const float* __restrict__ b,
                       float* __restrict__ o) {
    int i = blockIdx.x * 256 + threadIdx.x;
    if (i < 512) o[i] = a[i];
    else if (i < 1024) o[i] = b[i - 512];
}

__global__ void k_zero(unsigned* p) { if (threadIdx.x == 0) *p = 0u; }

// ---------------- conv1 v3: direct-global MFMA ----------------
// x[512][3][120][160] f32 -> a1 NHWC [512*1131 rows][32] bf16.
// One wave = one 16-row m-tile. 12 independent float4 loads in flight per lane.
__global__ void __launch_bounds__(256) k_conv1_v3(const float* __restrict__ x,
                                                  const short* __restrict__ Wc,
                                                  const float* __restrict__ bias,
                                                  short* __restrict__ y) {
    __shared__ short ct[4][512];        // per-wave [16 px][32 oc]
    const int tid = threadIdx.x;
    const int w = tid >> 6, l = tid & 63;
    const int lr = l & 15, lg = l >> 4;
    const int t = blockIdx.x * 4 + w;   // 0..36191 exact (9048*4)
    short8 bf[6][2];
#pragma unroll
    for (int ks = 0; ks < 6; ++ks)
#pragma unroll
        for (int nf = 0; nf < 2; ++nf)
            bf[ks][nf] = *(const short8*)&Wc[(nf * 16 + lr) * 192 + ks * 32 + lg * 8];
    const float bc0 = bias[lr], bc1 = bias[16 + lr];
    unsigned m = (unsigned)(t * 16 + lr);
    unsigned n = m / 1131u, pix = m % 1131u;
    unsigned oh = pix / 39u, ow = pix - oh * 39u;
    const float* base = x + (size_t)n * 57600 + (oh * 4) * 160 + ow * 4;
    // issue all 12 loads first (independent), then convert+MFMA
    float4 f[6][2];
#pragma unroll
    for (int ks = 0; ks < 6; ++ks) {
        int ic = ks >> 1, kh = (ks & 1) * 4 + lg;
        const float* ap = base + ic * 19200 + kh * 160;
        f[ks][0] = *(const float4*)ap;
        f[ks][1] = *(const float4*)(ap + 4);
    }
    f32x4 acc[2] = {};
#pragma unroll
    for (int ks = 0; ks < 6; ++ks) {
        short8 a;
        a[0] = f2bs(f[ks][0].x); a[1] = f2bs(f[ks][0].y);
        a[2] = f2bs(f[ks][0].z); a[3] = f2bs(f[ks][0].w);
        a[4] = f2bs(f[ks][1].x); a[5] = f2bs(f[ks][1].y);
        a[6] = f2bs(f[ks][1].z); a[7] = f2bs(f[ks][1].w);
        acc[0] = MFMA16(a, bf[ks][0], acc[0]);
        acc[1] = MFMA16(a, bf[ks][1], acc[1]);
    }
#pragma unroll
    for (int j = 0; j < 4; ++j) {
        ct[w][(lg * 4 + j) * 32 + lr] = f2bs(fmaxf(acc[0][j] + bc0, 0.f));
        ct[w][(lg * 4 + j) * 32 + 16 + lr] = f2bs(fmaxf(acc[1][j] + bc1, 0.f));
    }
    int row = l >> 2, c8 = (l & 3) * 8;
    short8 v = *(const short8*)&ct[w][row * 32 + c8];
    *(short8*)&y[((size_t)t * 16 + row) * 32 + c8] = v;   // rows are globally linear
}

// ---------------- conv2: a1 NHWC -> a2 NHWC [n][234 px][64] ----------------
__global__ void __launch_bounds__(256, 2) k_conv2_v2(const short* __restrict__ a1,
                                                     const short* __restrict__ Wc,
                                                     const float* __restrict__ bias,
                                                     short* __restrict__ y) {
    __shared__ short img[36192];        // [29][39][32] swizzled
    __shared__ short ct[2][1024];       // [parity][16 px][64 oc]
    const int n = blockIdx.x, tid = threadIdx.x;
    const int w = tid >> 6, l = tid & 63, lr = l & 15, lg = l >> 4;
    const int par = w >> 1, nfh = w & 1;
    short8 bfg[16][2];
#pragma unroll
    for (int ks = 0; ks < 16; ++ks)
#pragma unroll
        for (int q2 = 0; q2 < 2; ++q2)
            bfg[ks][q2] = *(const short8*)&Wc[(nfh * 32 + q2 * 16 + lr) * 512 + ks * 32 + lg * 8];
    float bc[2] = {bias[nfh * 32 + lr], bias[nfh * 32 + 16 + lr]};
    const short* src = a1 + (size_t)n * 36192;
    for (int it = 0; it < 18; ++it) {
        int i8 = it * 256 + tid;
        if (i8 < 4524) {
            short8 v = *(const short8*)(src + i8 * 8);
            int b = i8 * 16;
            b ^= ((b >> 7) & 7) << 4;
            *(short8*)((char*)img + b) = v;
        }
    }
    __syncthreads();
    for (int t = par; t < 16; t += 2) {
        int p = t * 16 + lr;
        int pc = p < 234 ? p : 233;
        int oh = pc / 18, ow = pc - oh * 18;
        int base = (oh * 2 * 39 + ow * 2) * 64 + lg * 16;
        f32x4 acc[2] = {};
#pragma unroll
        for (int ks = 0; ks < 16; ++ks) {
            int kh = ks >> 2, kw = ks & 3;
            int b = base + (kh * 39 + kw) * 64;
            b ^= ((b >> 7) & 7) << 4;
            short8 a = *(const short8*)((const char*)img + b);
            acc[0] = MFMA16(a, bfg[ks][0], acc[0]);
            acc[1] = MFMA16(a, bfg[ks][1], acc[1]);
        }
#pragma unroll
        for (int q2 = 0; q2 < 2; ++q2)
#pragma unroll
            for (int j = 0; j < 4; ++j)
                ct[par][(lg * 4 + j) * 64 + nfh * 32 + q2 * 16 + lr] =
                    f2bs(fmaxf(acc[q2][j] + bc[q2], 0.f));
        __syncthreads();
        int li = nfh * 64 + l;
        int row = li >> 3, c8 = (li & 7) * 8;
        short8 v = *(const short8*)&ct[par][row * 64 + c8];
        int pg = t * 16 + row;
        if (pg < 234)
            *(short8*)&y[((size_t)n * 234 + pg) * 64 + c8] = v;
        __syncthreads();
    }
}

// ---------------- conv3: a2 NHWC -> a3 NHWC [n][176 px][64] ----------------
__global__ void __launch_bounds__(256, 2) k_conv3_v2(const short* __restrict__ a2,
                                                     const short* __restrict__ Wc,
                                                     const float* __restrict__ bias,
                                                     short* __restrict__ y) {
    __shared__ short img[14976];        // [13][18][64] swizzled
    __shared__ short ct[2][1024];
    const int n = blockIdx.x, tid = threadIdx.x;
    const int w = tid >> 6, l = tid & 63, lr = l & 15, lg = l >> 4;
    const int par = w >> 1, nfh = w & 1;
    short8 bfg[18][2];
#pragma unroll
    for (int ks = 0; ks < 18; ++ks)
#pragma unroll
        for (int q2 = 0; q2 < 2; ++q2)
            bfg[ks][q2] = *(const short8*)&Wc[(nfh * 32 + q2 * 16 + lr) * 576 + ks * 32 + lg * 8];
    float bc[2] = {bias[nfh * 32 + lr], bias[nfh * 32 + 16 + lr]};
    const short* src = a2 + (size_t)n * 14976;
    for (int it = 0; it < 8; ++it) {
        int i8 = it * 256 + tid;
        if (i8 < 1872) {
            short8 v = *(const short8*)(src + i8 * 8);
            int b = i8 * 16;
            b ^= ((b >> 7) & 7) << 4;
            *(short8*)((char*)img + b) = v;
        }
    }
    __syncthreads();
    for (int t = par; t < 12; t += 2) {
        int p = t * 16 + lr;
        int pc = p < 176 ? p : 175;
        int oh = pc >> 4, ow = pc & 15;
        int base = (oh * 18 + ow) * 128 + lg * 16;
        f32x4 acc[2] = {};
#pragma unroll
        for (int ks = 0; ks < 18; ++ks) {
            int kh = ks / 6, r6 = ks % 6, kw = r6 >> 1, ich = r6 & 1;
            int b = base + (kh * 18 + kw) * 128 + ich * 64;
            b ^= ((b >> 7) & 7) << 4;
            short8 a = *(const short8*)((const char*)img + b);
            acc[0] = MFMA16(a, bfg[ks][0], acc[0]);
            acc[1] = MFMA16(a, bfg[ks][1], acc[1]);
        }
#pragma unroll
        for (int q2 = 0; q2 < 2; ++q2)
#pragma unroll
            for (int j = 0; j < 4; ++j)
                ct[par][(lg * 4 + j) * 64 + nfh * 32 + q2 * 16 + lr] =
                    f2bs(fmaxf(acc[q2][j] + bc[q2], 0.f));
        __syncthreads();
        int li = nfh * 64 + l;
        int row = li >> 3, c8 = (li & 7) * 8;
        short8 v = *(const short8*)&ct[par][row * 64 + c8];
        int pg = t * 16 + row;
        if (pg < 176)
            *(short8*)&y[((size_t)n * 176 + pg) * 64 + c8] = v;
        __syncthreads();
    }
}

// ---------------- MFMA GEMM core: part[z][M][N] = A @ W^T ----------------
__global__ void k_gemm_mfma(const short* __restrict__ A, const short* __restrict__ W,
                            float* __restrict__ part, int M, int N, int K, int kPerSplit) {
    __shared__ short As[64 * 40];
    __shared__ short Ws[64 * 40];
    const int tid = threadIdx.x;
    const int m0 = blockIdx.y * 64, n0 = blockIdx.x * 64;
    const int k0s = blockIdx.z * kPerSplit, k0e = k0s + kPerSplit;
    const int w = tid >> 6, l = tid & 63;
    const int wr = w >> 1, wc = w & 1;
    const int sr = tid >> 2, sc = tid & 3;
    const int lr = l & 15, lg = l >> 4;
    f32x4 acc[2][2] = {};
    for (int k0 = k0s; k0 < k0e; k0 += 32) {
        short8 av = *(const short8*)(A + (size_t)(m0 + sr) * K + k0 + sc * 8);
        short8 wv = *(const short8*)(W + (size_t)(n0 + sr) * K + k0 + sc * 8);
        __syncthreads();
        *(short8*)&As[sr * 40 + sc * 8] = av;
        *(short8*)&Ws[sr * 40 + sc * 8] = wv;
        __syncthreads();
        int cb = lg * 8;
        short8 a0 = *(const short8*)&As[(wr * 32 + lr) * 40 + cb];
        short8 a1 = *(const short8*)&As[(wr * 32 + 16 + lr) * 40 + cb];
        short8 b0 = *(const short8*)&Ws[(wc * 32 + lr) * 40 + cb];
        short8 b1 = *(const short8*)&Ws[(wc * 32 + 16 + lr) * 40 + cb];
        acc[0][0] = MFMA16(a0, b0, acc[0][0]);
        acc[0][1] = MFMA16(a0, b1, acc[0][1]);
        acc[1][0] = MFMA16(a1, b0, acc[1][0]);
        acc[1][1] = MFMA16(a1, b1, acc[1][1]);
    }
    float* pp = part + (size_t)blockIdx.z * M * N;
#pragma unroll
    for (int mi = 0; mi < 2; ++mi)
#pragma unroll
        for (int ni = 0; ni < 2; ++ni)
#pragma unroll
            for (int j = 0; j < 4; ++j) {
                int row = m0 + wr * 32 + mi * 16 + lg * 4 + j;
                int col = n0 + wc * 32 + ni * 16 + lr;
                pp[(size_t)row * N + col] = acc[mi][ni][j];
            }
}

__global__ void k_epilogue(const float* __restrict__ part, const float* __restrict__ bias,
                           short* __restrict__ out_b, float* __restrict__ out_f,
                           int MN, int N, int S, float slope) {
    int i = (blockIdx.x * 256 + threadIdx.x) * 4;
    if (i >= MN) return;
    float4 v = *(const float4*)(part + i);
    for (int s = 1; s < S; ++s) {
        float4 p = *(const float4*)(part + (size_t)s * MN + i);
        v.x += p.x; v.y += p.y; v.z += p.z; v.w += p.w;
    }
    float4 b = *(const float4*)(bias + (i % N));
    v.x += b.x; v.y += b.y; v.z += b.z; v.w += b.w;
    v.x = (v.x >= 0.f) ? v.x : v.x * slope;
    v.y = (v.y >= 0.f) ? v.y : v.y * slope;
    v.z = (v.z >= 0.f) ? v.z : v.z * slope;
    v.w = (v.w >= 0.f) ? v.w : v.w * slope;
    if (out_b) {
        out_b[i + 0] = f2bs(v.x); out_b[i + 1] = f2bs(v.y);
        out_b[i + 2] = f2bs(v.z); out_b[i + 3] = f2bs(v.w);
    }
    if (out_f) *(float4*)(out_f + i) = v;
}

// ---------------- persistent LSTM: ONE launch, 32 blocks, spin-barrier per step ----------------
// Block hb owns h-cols [hb*16, hb*16+16). Weights (64 rows) in registers for all 16 steps.
// c-state in registers. hm ping-pong in global, device-scope barrier between steps.
__global__ void __launch_bounds__(256, 1) k_lstm_all(
        const float* __restrict__ P, const short* __restrict__ Whhb,
        const int* __restrict__ done, short* __restrict__ hm0,
        short* __restrict__ hm1, const float* __restrict__ c0,
        short* __restrict__ nh, float* __restrict__ outH, float* __restrict__ outC,
        unsigned* __restrict__ barrier_cnt) {
    __shared__ short hs[32 * 520];
    __shared__ float gb[4][512];
    const int hb = blockIdx.x;
    const int tid = threadIdx.x, w = tid >> 6, l = tid & 63, lr = l & 15, lg = l >> 4;
    // weights: wave w = gate w, rows hb*16+lr within gate
    short8 bfg[16];
    const short* wrow = Whhb + (size_t)(w * 512 + hb * 16 + lr) * 512;
#pragma unroll
    for (int ks = 0; ks < 16; ++ks) bfg[ks] = *(const short8*)(wrow + ks * 32 + lg * 8);
    // c-state: idx = tid*2+q2 -> (batch = idx>>4, h = idx&15)
    float cr[2];
#pragma unroll
    for (int q2 = 0; q2 < 2; ++q2) {
        int idx = tid * 2 + q2;
        cr[q2] = c0[(idx >> 4) * 512 + hb * 16 + (idx & 15)];
    }
    for (int t = 0; t < 16; ++t) {
        const short* hin = (t & 1) ? hm1 : hm0;
        short* hout      = (t & 1) ? hm0 : hm1;
        for (int it = 0; it < 8; ++it) {
            int i8 = it * 256 + tid;
            short8 v = *(const short8*)(hin + i8 * 8);
            *(short8*)&hs[(i8 >> 6) * 520 + (i8 & 63) * 8] = v;
        }
        __syncthreads();
        f32x4 acc[2] = {};
#pragma unroll
        for (int ks = 0; ks < 16; ++ks) {
            short8 a0 = *(const short8*)&hs[lr * 520 + ks * 32 + lg * 8];
            short8 a1 = *(const short8*)&hs[(16 + lr) * 520 + ks * 32 + lg * 8];
            acc[0] = MFMA16(a0, bfg[ks], acc[0]);
            acc[1] = MFMA16(a1, bfg[ks], acc[1]);
        }
#pragma unroll
        for (int mt = 0; mt < 2; ++mt)
#pragma unroll
            for (int j = 0; j < 4; ++j) {
                int batch = mt * 16 + lg * 4 + j;
                gb[w][batch * 16 + lr] =
                    acc[mt][j] + P[(size_t)(t * 32 + batch) * 2048 + w * 512 + hb * 16 + lr];
            }
        __syncthreads();
#pragma unroll
        for (int q2 = 0; q2 < 2; ++q2) {
            int idx = tid * 2 + q2;
            int batch = idx >> 4, h = idx & 15;
            float m = 1.f - (float)done[t * 32 + batch];
            float ig = 1.f / (1.f + expf(-gb[0][idx]));
            float fg = 1.f / (1.f + expf(-gb[1][idx]));
            float gt = tanhf(gb[2][idx]);
            float og = 1.f / (1.f + expf(-gb[3][idx]));
            float cn = fg * (cr[q2] * m) + ig * gt;
            float hn = og * tanhf(cn);
            cr[q2] = cn;
            int ci = batch * 512 + hb * 16 + h;
            nh[(size_t)(t * 32 + batch) * 512 + hb * 16 + h] = f2bs(hn);
            if (t < 15) {
                float m2 = 1.f - (float)done[(t + 1) * 32 + batch];
                hout[ci] = f2bs(hn * m2);
            } else {
                outH[ci] = hn;
                outC[ci] = cn;
            }
        }
        if (t < 15) {
            __syncthreads();              // all LDS reads done before next overwrite
            __threadfence();              // release hout writes (agent scope)
            if (tid == 0) {
                __hip_atomic_fetch_add(barrier_cnt, 1u, __ATOMIC_ACQ_REL,
                                       __HIP_MEMORY_SCOPE_AGENT);
                while (__hip_atomic_load(barrier_cnt, __ATOMIC_ACQUIRE,
                                         __HIP_MEMORY_SCOPE_AGENT) < 32u * (unsigned)(t + 1))
                    __builtin_amdgcn_s_sleep(1);
            }
            __syncthreads();
        }
    }
}

// ---------------- small heads: logits [512][8] + value [512] from combined aAC ----------------
__global__ void k_heads(const short* __restrict__ aAC,
                        const short* __restrict__ A2b, const float* __restrict__ Ab2,
                        const short* __restrict__ C2b, const float* __restrict__ Cb2,
                        float* __restrict__ out) {
    int idx = blockIdx.x * 4 + (threadIdx.x >> 6);
    int l = threadIdx.x & 63;
    if (idx >= 4608) return;
    int row = idx / 9, col = idx % 9;
    const short* act = aAC + (size_t)row * 1024 + (col < 8 ? 0 : 512);
    const short* wr  = (col < 8) ? (A2b + (size_t)col * 512) : C2b;
    short8 a = *(const short8*)(act + l * 8);
    short8 wv = *(const short8*)(wr + l * 8);
    float s = 0.f;
#pragma unroll
    for (int q = 0; q < 8; ++q) s += bs2f(a[q]) * bs2f(wv[q]);
#pragma unroll
    for (int off = 32; off > 0; off >>= 1) s += __shfl_xor(s, off, 64);
    if (l == 0) {
        if (col < 8) out[row * 8 + col] = s + Ab2[col];
        else out[4096 + row] = s + Cb2[0];
    }
}

// ---------------- launch ----------------

extern "C" void kernel_launch(void* const* d_in, const int* in_sizes, int n_in,
                              void* d_out, int out_size, void* d_ws, size_t ws_size,
                              hipStream_t stream) {
    (void)in_sizes; (void)n_in; (void)out_size; (void)ws_size;
    const float* x    = (const float*)d_in[0];
    const int*   done = (const int*)  d_in[1];
    const float* h0   = (const float*)d_in[2];
    const float* c0   = (const float*)d_in[3];
    const float* w1   = (const float*)d_in[4];
    const float* b1   = (const float*)d_in[5];
    const float* w2   = (const float*)d_in[6];
    const float* b2   = (const float*)d_in[7];
    const float* w3   = (const float*)d_in[8];
    const float* b3   = (const float*)d_in[9];
    const float* fcW  = (const float*)d_in[10];
    const float* fcb  = (const float*)d_in[11];
    const float* Wih  = (const float*)d_in[12];
    const float* Whh  = (const float*)d_in[13];
    const float* bih  = (const float*)d_in[14];
    const float* bhh  = (const float*)d_in[15];
    const float* A1   = (const float*)d_in[16];
    const float* Ab1  = (const float*)d_in[17];
    const float* A2   = (const float*)d_in[18];
    const float* Ab2  = (const float*)d_in[19];
    const float* C1   = (const float*)d_in[20];
    const float* Cb1  = (const float*)d_in[21];
    const float* C2   = (const float*)d_in[22];
    const float* Cb2  = (const float*)d_in[23];
    float* out = (float*)d_out;

    char* wsp = (char*)d_ws;
    auto alloc = [&](size_t bytes) {
        char* p = wsp; wsp += (bytes + 255) & ~(size_t)255; return p;
    };
    short* a1s  = (short*)alloc(18530304ull * 2);  // [512*1131][32]
    short* a2s  = (short*)alloc(7667712ull * 2);   // [512*234][64]
    short* a3s  = (short*)alloc(5767168ull * 2);   // [512*176][64]
    short* hfc  = (short*)alloc(262144ull * 2);    // [512][512]
    float* P    = (float*)alloc(1048576ull * 4);   // [512][2048]
    short* whhb = (short*)alloc(1048576ull * 2);   // Whh bf16 [2048][512]
    short* hm0  = (short*)alloc(16384ull * 2);
    short* hm1  = (short*)alloc(16384ull * 2);
    short* nh   = (short*)alloc(262144ull * 2);
    short* aAC  = (short*)alloc(524288ull * 2);    // [512][1024] combined actor/critic hidden
    float* part = (float*)alloc(1048576ull * 4);
    short* wc1  = (short*)alloc(6144ull * 2);
    short* wc2  = (short*)alloc(32768ull * 2);
    short* wc3  = (short*)alloc(36864ull * 2);
    short* fcwr = (short*)alloc(5767168ull * 2);
    short* wihb = (short*)alloc(1048576ull * 2);
    short* a1b  = (short*)alloc(262144ull * 2);    // A1 bf16 [512][512]
    short* c1b  = (short*)alloc(262144ull * 2);    // C1 bf16 (contiguous after a1b)
    short* a2b  = (short*)alloc(4096ull * 2);
    short* c2b  = (short*)alloc(512ull * 2);
    float* bias2 = (float*)alloc(2048ull * 4);
    float* biasAC = (float*)alloc(1024ull * 4);
    unsigned* bar = (unsigned*)alloc(256);

    // prep
    k_cvt<<<6, 256, 0, stream>>>(w1, wc1, 1536);
    k_prep_wc2<<<128, 256, 0, stream>>>(w2, wc2);
    k_prep_wc3<<<144, 256, 0, stream>>>(w3, wc3);
    k_prep_fcw2<<<512, 256, 0, stream>>>(fcW, fcwr);
    k_cvt<<<1024, 256, 0, stream>>>(Wih, wihb, 262144);
    k_cvt<<<1024, 256, 0, stream>>>(Whh, whhb, 262144);
    k_cvt<<<256, 256, 0, stream>>>(A1, a1b, 65536);
    k_cvt<<<256, 256, 0, stream>>>(C1, c1b, 65536);
    k_cvt<<<4, 256, 0, stream>>>(A2, a2b, 1024);
    k_cvt<<<1, 256, 0, stream>>>(C2, c2b, 128);
    k_prep_hm<<<64, 256, 0, stream>>>(h0, done, hm0);
    k_bias2<<<8, 256, 0, stream>>>(bih, bhh, bias2);
    k_cat2<<<4, 256, 0, stream>>>(Ab1, Cb1, biasAC);
    k_zero<<<1, 64, 0, stream>>>(bar);

    // convs
    k_conv1_v3<<<9048, 256, 0, stream>>>(x, wc1, b1, a1s);
    k_conv2_v2<<<512, 256, 0, stream>>>(a1s, wc2, b2, a2s);
    k_conv3_v2<<<512, 256, 0, stream>>>(a2s, wc3, b3, a3s);

    // FC: split-K 4
    k_gemm_mfma<<<dim3(8, 8, 4), 256, 0, stream>>>(a3s, fcwr, part, 512, 512, 11264, 2816);
    k_epilogue<<<256, 256, 0, stream>>>(part, fcb, hfc, nullptr, 262144, 512, 4, 0.2f);

    // P = hfc @ Wih^T + (bih + bhh)
    k_gemm_mfma<<<dim3(32, 8, 1), 256, 0, stream>>>(hfc, wihb, part, 512, 2048, 512, 512);
    k_epilogue<<<1024, 256, 0, stream>>>(part, bias2, nullptr, P, 1048576, 2048, 1, 1.0f);

    // LSTM: one persistent launch (32 blocks co-resident; writes hT/cT to out directly)
    k_lstm_all<<<32, 256, 0, stream>>>(P, whhb, done, hm0, hm1, c0, nh,
                                       out + 4608, out + 20992, bar);

    // heads: combined [A1;C1] GEMM -> aAC [512][1024]
    k_gemm_mfma<<<dim3(16, 8, 1), 256, 0, stream>>>(nh, a1b, part, 512, 1024, 512, 512);
    k_epilogue<<<512, 256, 0, stream>>>(part, biasAC, aAC, nullptr, 524288, 1024, 1, 0.01f);
    k_heads<<<1152, 256, 0, stream>>>(aAC, a2b, Ab2, c2b, Cb2, out);
}

// Round 6
// 287.688 us; speedup vs baseline: 1.0602x; 1.0602x over previous
//
#include <hip/hip_runtime.h>
#include <hip/hip_bf16.h>
#include <math.h>

using short8 = __attribute__((ext_vector_type(8))) short;   // 8 bf16 (4 VGPR)
using f32x4  = __attribute__((ext_vector_type(4))) float;   // MFMA acc
typedef unsigned long long u64;

#define MFMA16(a, b, c) __builtin_amdgcn_mfma_f32_16x16x32_bf16(a, b, c, 0, 0, 0)

__device__ __forceinline__ short f2bs(float f) {
    __hip_bfloat16 h = __float2bfloat16(f);          // RNE
    return __builtin_bit_cast(short, h);
}
__device__ __forceinline__ float bs2f(short s) {
    return __uint_as_float(((unsigned)(unsigned short)s) << 16);
}
__device__ __forceinline__ unsigned pk2(float a, float b) {
    return ((unsigned)(unsigned short)f2bs(a)) | (((unsigned)(unsigned short)f2bs(b)) << 16);
}

// ---------------- mega-prep: all weight conversions + transposes in ONE launch ----------------
__global__ void __launch_bounds__(256) k_megaprep(
        const float* __restrict__ w1, const float* __restrict__ w2,
        const float* __restrict__ w3, const float* __restrict__ fcW,
        const float* __restrict__ Wih, const float* __restrict__ Whh,
        const float* __restrict__ A1, const float* __restrict__ C1,
        const float* __restrict__ A2, const float* __restrict__ C2,
        const float* __restrict__ h0, const int* __restrict__ done,
        const float* __restrict__ bih, const float* __restrict__ bhh,
        const float* __restrict__ Ab1, const float* __restrict__ Cb1,
        short* __restrict__ wc1, short* __restrict__ wc2, short* __restrict__ wc3,
        short* __restrict__ fcwr, short* __restrict__ wihb, short* __restrict__ whhb,
        short* __restrict__ a1b, short* __restrict__ c1b, short* __restrict__ a2b,
        short* __restrict__ c2b, short* __restrict__ hm0,
        float* __restrict__ bias2, float* __restrict__ biasAC, unsigned* __restrict__ bar) {
    __shared__ short t[176 * 76];
    const int bid = blockIdx.x, tid = threadIdx.x;

    auto cvt4 = [&](const float* in, short* out, int i) {
        float4 v = *(const float4*)(in + i * 4);
        out[i * 4 + 0] = f2bs(v.x); out[i * 4 + 1] = f2bs(v.y);
        out[i * 4 + 2] = f2bs(v.z); out[i * 4 + 3] = f2bs(v.w);
    };

    if (bid < 512) {
        // fcW [512][11264] (K = oc*176+pix) -> fcwr [512][pix*64+oc]
        int r = bid;
        for (int it = 0; it < 11; ++it) {
            int c4 = it * 256 + tid;
            float4 v = *(const float4*)(fcW + (size_t)r * 11264 + c4 * 4);
            int c = c4 * 4;
            int oc = c / 176, pix = c % 176;
            t[(pix + 0) * 76 + oc] = f2bs(v.x);
            t[(pix + 1) * 76 + oc] = f2bs(v.y);
            t[(pix + 2) * 76 + oc] = f2bs(v.z);
            t[(pix + 3) * 76 + oc] = f2bs(v.w);
        }
        __syncthreads();
        for (int it = 0; it < 6; ++it) {
            int j8 = it * 256 + tid;
            if (j8 < 1408) {
                int j = j8 * 8, pix = j >> 6, oc0 = j & 63;
                const short* tp = &t[pix * 76 + oc0];
                short8 v;
                ((uint2*)&v)[0] = *(const uint2*)tp;
                ((uint2*)&v)[1] = *(const uint2*)(tp + 4);
                *(short8*)&fcwr[(size_t)r * 11264 + j] = v;
            }
        }
    } else if (bid < 1536) {
        cvt4(Wih, wihb, (bid - 512) * 256 + tid);
    } else if (bid < 2560) {
        cvt4(Whh, whhb, (bid - 1536) * 256 + tid);
    } else if (bid < 2816) {
        cvt4(A1, a1b, (bid - 2560) * 256 + tid);
    } else if (bid < 3072) {
        cvt4(C1, c1b, (bid - 2816) * 256 + tid);
    } else if (bid < 3078) {
        cvt4(w1, wc1, (bid - 3072) * 256 + tid);       // layout already (ic*64+kh*8+kw)
    } else if (bid < 3206) {
        int i = (bid - 3078) * 256 + tid;              // 32768
        int oc = i >> 9, col = i & 511;
        int kh = col >> 7, kw = (col >> 5) & 3, ic = col & 31;
        wc2[i] = f2bs(w2[((oc * 32 + ic) * 4 + kh) * 4 + kw]);
    } else if (bid < 3350) {
        int i = (bid - 3206) * 256 + tid;              // 36864
        int oc = i / 576, col = i % 576;
        int kh = col / 192, r = col % 192, kw = r >> 6, ic = r & 63;
        wc3[i] = f2bs(w3[((oc * 64 + ic) * 3 + kh) * 3 + kw]);
    } else if (bid < 3354) {
        cvt4(A2, a2b, (bid - 3350) * 256 + tid);
    } else if (bid < 3355) {
        if (tid < 128) cvt4(C2, c2b, tid);
    } else if (bid < 3419) {
        int i = (bid - 3355) * 256 + tid;              // 16384
        float m = 1.f - (float)done[i >> 9];
        hm0[i] = f2bs(h0[i] * m);
    } else if (bid < 3427) {
        int i = (bid - 3419) * 256 + tid;              // 2048
        bias2[i] = bih[i] + bhh[i];
    } else if (bid < 3431) {
        int i = (bid - 3427) * 256 + tid;              // 1024
        biasAC[i] = (i < 512) ? Ab1[i] : Cb1[i - 512];
    } else {
        if (tid == 0) *bar = 0u;
    }
}

// ---------------- conv1 v3: direct-global MFMA ----------------
__global__ void __launch_bounds__(256) k_conv1_v3(const float* __restrict__ x,
                                                  const short* __restrict__ Wc,
                                                  const float* __restrict__ bias,
                                                  short* __restrict__ y) {
    __shared__ short ct[4][512];        // per-wave [16 px][32 oc]
    const int tid = threadIdx.x;
    const int w = tid >> 6, l = tid & 63;
    const int lr = l & 15, lg = l >> 4;
    const int t = blockIdx.x * 4 + w;   // 0..36191 exact (9048*4)
    short8 bf[6][2];
#pragma unroll
    for (int ks = 0; ks < 6; ++ks)
#pragma unroll
        for (int nf = 0; nf < 2; ++nf)
            bf[ks][nf] = *(const short8*)&Wc[(nf * 16 + lr) * 192 + ks * 32 + lg * 8];
    const float bc0 = bias[lr], bc1 = bias[16 + lr];
    unsigned m = (unsigned)(t * 16 + lr);
    unsigned n = m / 1131u, pix = m % 1131u;
    unsigned oh = pix / 39u, ow = pix - oh * 39u;
    const float* base = x + (size_t)n * 57600 + (oh * 4) * 160 + ow * 4;
    float4 f[6][2];
#pragma unroll
    for (int ks = 0; ks < 6; ++ks) {
        int ic = ks >> 1, kh = (ks & 1) * 4 + lg;
        const float* ap = base + ic * 19200 + kh * 160;
        f[ks][0] = *(const float4*)ap;
        f[ks][1] = *(const float4*)(ap + 4);
    }
    f32x4 acc[2] = {};
#pragma unroll
    for (int ks = 0; ks < 6; ++ks) {
        short8 a;
        a[0] = f2bs(f[ks][0].x); a[1] = f2bs(f[ks][0].y);
        a[2] = f2bs(f[ks][0].z); a[3] = f2bs(f[ks][0].w);
        a[4] = f2bs(f[ks][1].x); a[5] = f2bs(f[ks][1].y);
        a[6] = f2bs(f[ks][1].z); a[7] = f2bs(f[ks][1].w);
        acc[0] = MFMA16(a, bf[ks][0], acc[0]);
        acc[1] = MFMA16(a, bf[ks][1], acc[1]);
    }
#pragma unroll
    for (int j = 0; j < 4; ++j) {
        ct[w][(lg * 4 + j) * 32 + lr] = f2bs(fmaxf(acc[0][j] + bc0, 0.f));
        ct[w][(lg * 4 + j) * 32 + 16 + lr] = f2bs(fmaxf(acc[1][j] + bc1, 0.f));
    }
    int row = l >> 2, c8 = (l & 3) * 8;
    short8 v = *(const short8*)&ct[w][row * 32 + c8];
    *(short8*)&y[((size_t)t * 16 + row) * 32 + c8] = v;
}

// ---------------- conv2: a1 NHWC -> a2 NHWC [n][234 px][64] ----------------
__global__ void __launch_bounds__(256, 2) k_conv2_v2(const short* __restrict__ a1,
                                                     const short* __restrict__ Wc,
                                                     const float* __restrict__ bias,
                                                     short* __restrict__ y) {
    __shared__ short img[36192];        // [29][39][32] swizzled
    __shared__ short ct[2][1024];
    const int n = blockIdx.x, tid = threadIdx.x;
    const int w = tid >> 6, l = tid & 63, lr = l & 15, lg = l >> 4;
    const int par = w >> 1, nfh = w & 1;
    short8 bfg[16][2];
#pragma unroll
    for (int ks = 0; ks < 16; ++ks)
#pragma unroll
        for (int q2 = 0; q2 < 2; ++q2)
            bfg[ks][q2] = *(const short8*)&Wc[(nfh * 32 + q2 * 16 + lr) * 512 + ks * 32 + lg * 8];
    float bc[2] = {bias[nfh * 32 + lr], bias[nfh * 32 + 16 + lr]};
    const short* src = a1 + (size_t)n * 36192;
    for (int it = 0; it < 18; ++it) {
        int i8 = it * 256 + tid;
        if (i8 < 4524) {
            short8 v = *(const short8*)(src + i8 * 8);
            int b = i8 * 16;
            b ^= ((b >> 7) & 7) << 4;
            *(short8*)((char*)img + b) = v;
        }
    }
    __syncthreads();
    for (int t = par; t < 16; t += 2) {
        int p = t * 16 + lr;
        int pc = p < 234 ? p : 233;
        int oh = pc / 18, ow = pc - oh * 18;
        int base = (oh * 2 * 39 + ow * 2) * 64 + lg * 16;
        f32x4 acc[2] = {};
#pragma unroll
        for (int ks = 0; ks < 16; ++ks) {
            int kh = ks >> 2, kw = ks & 3;
            int b = base + (kh * 39 + kw) * 64;
            b ^= ((b >> 7) & 7) << 4;
            short8 a = *(const short8*)((const char*)img + b);
            acc[0] = MFMA16(a, bfg[ks][0], acc[0]);
            acc[1] = MFMA16(a, bfg[ks][1], acc[1]);
        }
#pragma unroll
        for (int q2 = 0; q2 < 2; ++q2)
#pragma unroll
            for (int j = 0; j < 4; ++j)
                ct[par][(lg * 4 + j) * 64 + nfh * 32 + q2 * 16 + lr] =
                    f2bs(fmaxf(acc[q2][j] + bc[q2], 0.f));
        __syncthreads();
        int li = nfh * 64 + l;
        int row = li >> 3, c8 = (li & 7) * 8;
        short8 v = *(const short8*)&ct[par][row * 64 + c8];
        int pg = t * 16 + row;
        if (pg < 234)
            *(short8*)&y[((size_t)n * 234 + pg) * 64 + c8] = v;
        __syncthreads();
    }
}

// ---------------- conv3: a2 NHWC -> a3 NHWC [n][176 px][64] ----------------
__global__ void __launch_bounds__(256, 2) k_conv3_v2(const short* __restrict__ a2,
                                                     const short* __restrict__ Wc,
                                                     const float* __restrict__ bias,
                                                     short* __restrict__ y) {
    __shared__ short img[14976];        // [13][18][64] swizzled
    __shared__ short ct[2][1024];
    const int n = blockIdx.x, tid = threadIdx.x;
    const int w = tid >> 6, l = tid & 63, lr = l & 15, lg = l >> 4;
    const int par = w >> 1, nfh = w & 1;
    short8 bfg[18][2];
#pragma unroll
    for (int ks = 0; ks < 18; ++ks)
#pragma unroll
        for (int q2 = 0; q2 < 2; ++q2)
            bfg[ks][q2] = *(const short8*)&Wc[(nfh * 32 + q2 * 16 + lr) * 576 + ks * 32 + lg * 8];
    float bc[2] = {bias[nfh * 32 + lr], bias[nfh * 32 + 16 + lr]};
    const short* src = a2 + (size_t)n * 14976;
    for (int it = 0; it < 8; ++it) {
        int i8 = it * 256 + tid;
        if (i8 < 1872) {
            short8 v = *(const short8*)(src + i8 * 8);
            int b = i8 * 16;
            b ^= ((b >> 7) & 7) << 4;
            *(short8*)((char*)img + b) = v;
        }
    }
    __syncthreads();
    for (int t = par; t < 12; t += 2) {
        int p = t * 16 + lr;
        int pc = p < 176 ? p : 175;
        int oh = pc >> 4, ow = pc & 15;
        int base = (oh * 18 + ow) * 128 + lg * 16;
        f32x4 acc[2] = {};
#pragma unroll
        for (int ks = 0; ks < 18; ++ks) {
            int kh = ks / 6, r6 = ks % 6, kw = r6 >> 1, ich = r6 & 1;
            int b = base + (kh * 18 + kw) * 128 + ich * 64;
            b ^= ((b >> 7) & 7) << 4;
            short8 a = *(const short8*)((const char*)img + b);
            acc[0] = MFMA16(a, bfg[ks][0], acc[0]);
            acc[1] = MFMA16(a, bfg[ks][1], acc[1]);
        }
#pragma unroll
        for (int q2 = 0; q2 < 2; ++q2)
#pragma unroll
            for (int j = 0; j < 4; ++j)
                ct[par][(lg * 4 + j) * 64 + nfh * 32 + q2 * 16 + lr] =
                    f2bs(fmaxf(acc[q2][j] + bc[q2], 0.f));
        __syncthreads();
        int li = nfh * 64 + l;
        int row = li >> 3, c8 = (li & 7) * 8;
        short8 v = *(const short8*)&ct[par][row * 64 + c8];
        int pg = t * 16 + row;
        if (pg < 176)
            *(short8*)&y[((size_t)n * 176 + pg) * 64 + c8] = v;
        __syncthreads();
    }
}

// ---------------- MFMA GEMM core: part[z][M][N] = A @ W^T (split-K, FC only) ----------------
__global__ void k_gemm_mfma(const short* __restrict__ A, const short* __restrict__ W,
                            float* __restrict__ part, int M, int N, int K, int kPerSplit) {
    __shared__ short As[64 * 40];
    __shared__ short Ws[64 * 40];
    const int tid = threadIdx.x;
    const int m0 = blockIdx.y * 64, n0 = blockIdx.x * 64;
    const int k0s = blockIdx.z * kPerSplit, k0e = k0s + kPerSplit;
    const int w = tid >> 6, l = tid & 63;
    const int wr = w >> 1, wc = w & 1;
    const int sr = tid >> 2, sc = tid & 3;
    const int lr = l & 15, lg = l >> 4;
    f32x4 acc[2][2] = {};
    for (int k0 = k0s; k0 < k0e; k0 += 32) {
        short8 av = *(const short8*)(A + (size_t)(m0 + sr) * K + k0 + sc * 8);
        short8 wv = *(const short8*)(W + (size_t)(n0 + sr) * K + k0 + sc * 8);
        __syncthreads();
        *(short8*)&As[sr * 40 + sc * 8] = av;
        *(short8*)&Ws[sr * 40 + sc * 8] = wv;
        __syncthreads();
        int cb = lg * 8;
        short8 a0 = *(const short8*)&As[(wr * 32 + lr) * 40 + cb];
        short8 a1 = *(const short8*)&As[(wr * 32 + 16 + lr) * 40 + cb];
        short8 b0 = *(const short8*)&Ws[(wc * 32 + lr) * 40 + cb];
        short8 b1 = *(const short8*)&Ws[(wc * 32 + 16 + lr) * 40 + cb];
        acc[0][0] = MFMA16(a0, b0, acc[0][0]);
        acc[0][1] = MFMA16(a0, b1, acc[0][1]);
        acc[1][0] = MFMA16(a1, b0, acc[1][0]);
        acc[1][1] = MFMA16(a1, b1, acc[1][1]);
    }
    float* pp = part + (size_t)blockIdx.z * M * N;
#pragma unroll
    for (int mi = 0; mi < 2; ++mi)
#pragma unroll
        for (int ni = 0; ni < 2; ++ni)
#pragma unroll
            for (int j = 0; j < 4; ++j) {
                int row = m0 + wr * 32 + mi * 16 + lg * 4 + j;
                int col = n0 + wc * 32 + ni * 16 + lr;
                pp[(size_t)row * N + col] = acc[mi][ni][j];
            }
}

// ---------------- GEMM with fused bias+leaky epilogue (S=1 cases) ----------------
__global__ void k_gemm_bias(const short* __restrict__ A, const short* __restrict__ W,
                            const float* __restrict__ bias, short* __restrict__ out_b,
                            float* __restrict__ out_f, int M, int N, int K, float slope) {
    __shared__ short As[64 * 40];
    __shared__ short Ws[64 * 40];
    const int tid = threadIdx.x;
    const int m0 = blockIdx.y * 64, n0 = blockIdx.x * 64;
    const int w = tid >> 6, l = tid & 63;
    const int wr = w >> 1, wc = w & 1;
    const int sr = tid >> 2, sc = tid & 3;
    const int lr = l & 15, lg = l >> 4;
    f32x4 acc[2][2] = {};
    for (int k0 = 0; k0 < K; k0 += 32) {
        short8 av = *(const short8*)(A + (size_t)(m0 + sr) * K + k0 + sc * 8);
        short8 wv = *(const short8*)(W + (size_t)(n0 + sr) * K + k0 + sc * 8);
        __syncthreads();
        *(short8*)&As[sr * 40 + sc * 8] = av;
        *(short8*)&Ws[sr * 40 + sc * 8] = wv;
        __syncthreads();
        int cb = lg * 8;
        short8 a0 = *(const short8*)&As[(wr * 32 + lr) * 40 + cb];
        short8 a1 = *(const short8*)&As[(wr * 32 + 16 + lr) * 40 + cb];
        short8 b0 = *(const short8*)&Ws[(wc * 32 + lr) * 40 + cb];
        short8 b1 = *(const short8*)&Ws[(wc * 32 + 16 + lr) * 40 + cb];
        acc[0][0] = MFMA16(a0, b0, acc[0][0]);
        acc[0][1] = MFMA16(a0, b1, acc[0][1]);
        acc[1][0] = MFMA16(a1, b0, acc[1][0]);
        acc[1][1] = MFMA16(a1, b1, acc[1][1]);
    }
#pragma unroll
    for (int mi = 0; mi < 2; ++mi)
#pragma unroll
        for (int ni = 0; ni < 2; ++ni)
#pragma unroll
            for (int j = 0; j < 4; ++j) {
                int row = m0 + wr * 32 + mi * 16 + lg * 4 + j;
                int col = n0 + wc * 32 + ni * 16 + lr;
                float v = acc[mi][ni][j] + bias[col];
                v = (v >= 0.f) ? v : v * slope;
                if (out_f) out_f[(size_t)row * N + col] = v;
                else       out_b[(size_t)row * N + col] = f2bs(v);
            }
}

// ---------------- persistent LSTM v2: fence-free atomic exchange ----------------
// Block hb owns h-cols [hb*16, hb*16+16). Exchange via AGENT-scope relaxed atomics
// (per-access sc flags -> coherent at L3; NO buffer_wbl2/inv in the loop).
__global__ void __launch_bounds__(256, 1) k_lstm_all2(
        const float* __restrict__ P, const short* __restrict__ Whhb,
        const int* __restrict__ done, u64* __restrict__ hq0, u64* __restrict__ hq1,
        const float* __restrict__ c0, short* __restrict__ nh,
        float* __restrict__ outH, float* __restrict__ outC, unsigned* __restrict__ bar) {
    __shared__ short hs[32 * 520];
    __shared__ float gb[4][512];
    unsigned* hsu = (unsigned*)hs;
    const int hb = blockIdx.x;
    const int tid = threadIdx.x, w = tid >> 6, l = tid & 63, lr = l & 15, lg = l >> 4;
    short8 bfg[16];
    const short* wrow = Whhb + (size_t)(w * 512 + hb * 16 + lr) * 512;
#pragma unroll
    for (int ks = 0; ks < 16; ++ks) bfg[ks] = *(const short8*)(wrow + ks * 32 + lg * 8);
    float cr[2];
#pragma unroll
    for (int q2 = 0; q2 < 2; ++q2) {
        int idx = tid * 2 + q2;
        cr[q2] = c0[(idx >> 4) * 512 + hb * 16 + (idx & 15)];
    }
    const int batch = (tid * 2) >> 4, h0c = (tid * 2) & 15;
    for (int t = 0; t < 16; ++t) {
        const u64* hin = (t & 1) ? hq1 : hq0;
        u64* hout      = (t & 1) ? hq0 : hq1;
        // stage h (full 32x512 bf16) via coherent qword loads
#pragma unroll
        for (int it = 0; it < 16; ++it) {
            int i = it * 256 + tid;
            u64 g = __hip_atomic_load(hin + i, __ATOMIC_RELAXED, __HIP_MEMORY_SCOPE_AGENT);
            *(u64*)&hs[(i >> 7) * 520 + (i & 127) * 4] = g;
        }
        __syncthreads();
        f32x4 acc[2] = {};
#pragma unroll
        for (int ks = 0; ks < 16; ++ks) {
            short8 a0 = *(const short8*)&hs[lr * 520 + ks * 32 + lg * 8];
            short8 a1 = *(const short8*)&hs[(16 + lr) * 520 + ks * 32 + lg * 8];
            acc[0] = MFMA16(a0, bfg[ks], acc[0]);
            acc[1] = MFMA16(a1, bfg[ks], acc[1]);
        }
#pragma unroll
        for (int mt = 0; mt < 2; ++mt)
#pragma unroll
            for (int j = 0; j < 4; ++j) {
                int bb = mt * 16 + lg * 4 + j;
                gb[w][bb * 16 + lr] =
                    acc[mt][j] + P[(size_t)(t * 32 + bb) * 2048 + w * 512 + hb * 16 + lr];
            }
        __syncthreads();
        float hnv[2];
#pragma unroll
        for (int q2 = 0; q2 < 2; ++q2) {
            int idx = tid * 2 + q2;
            float m = 1.f - (float)done[t * 32 + batch];
            float ig = 1.f / (1.f + expf(-gb[0][idx]));
            float fg = 1.f / (1.f + expf(-gb[1][idx]));
            float gt = tanhf(gb[2][idx]);
            float og = 1.f / (1.f + expf(-gb[3][idx]));
            float cn = fg * (cr[q2] * m) + ig * gt;
            hnv[q2] = og * tanhf(cn);
            cr[q2] = cn;
        }
        *(unsigned*)&nh[(size_t)(t * 32 + batch) * 512 + hb * 16 + h0c] = pk2(hnv[0], hnv[1]);
        if (t < 15) {
            float m2 = 1.f - (float)done[(t + 1) * 32 + batch];
            hsu[tid] = pk2(hnv[0] * m2, hnv[1] * m2);    // hs dead now; reuse as staging
            __syncthreads();
            if (tid < 128) {
                int bb = tid >> 2, j = tid & 3;
                unsigned lo2 = hsu[bb * 8 + 2 * j], hi2 = hsu[bb * 8 + 2 * j + 1];
                u64 q = (u64)lo2 | ((u64)hi2 << 32);
                __hip_atomic_store(hout + bb * 128 + hb * 4 + j, q,
                                   __ATOMIC_RELAXED, __HIP_MEMORY_SCOPE_AGENT);
            }
            asm volatile("s_waitcnt vmcnt(0)" ::: "memory");
            __syncthreads();                             // all waves' stores acked
            if (tid == 0) {
                __hip_atomic_fetch_add(bar, 1u, __ATOMIC_RELAXED, __HIP_MEMORY_SCOPE_AGENT);
                unsigned tgt = 32u * (unsigned)(t + 1);
                while (__hip_atomic_load(bar, __ATOMIC_RELAXED,
                                         __HIP_MEMORY_SCOPE_AGENT) < tgt)
                    __builtin_amdgcn_s_sleep(4);
            }
            __syncthreads();
        } else {
            int ci = batch * 512 + hb * 16 + h0c;
            outH[ci] = hnv[0]; outH[ci + 1] = hnv[1];
            outC[ci] = cr[0];  outC[ci + 1] = cr[1];
        }
    }
}

// ---------------- small heads: logits [512][8] + value [512] ----------------
__global__ void k_heads(const short* __restrict__ aAC,
                        const short* __restrict__ A2b, const float* __restrict__ Ab2,
                        const short* __restrict__ C2b, const float* __restrict__ Cb2,
                        float* __restrict__ out) {
    int idx = blockIdx.x * 4 + (threadIdx.x >> 6);
    int l = threadIdx.x & 63;
    if (idx >= 4608) return;
    int row = idx / 9, col = idx % 9;
    const short* act = aAC + (size_t)row * 1024 + (col < 8 ? 0 : 512);
    const short* wr  = (col < 8) ? (A2b + (size_t)col * 512) : C2b;
    short8 a = *(const short8*)(act + l * 8);
    short8 wv = *(const short8*)(wr + l * 8);
    float s = 0.f;
#pragma unroll
    for (int q = 0; q < 8; ++q) s += bs2f(a[q]) * bs2f(wv[q]);
#pragma unroll
    for (int off = 32; off > 0; off >>= 1) s += __shfl_xor(s, off, 64);
    if (l == 0) {
        if (col < 8) out[row * 8 + col] = s + Ab2[col];
        else out[4096 + row] = s + Cb2[0];
    }
}

// ---------------- launch ----------------

extern "C" void kernel_launch(void* const* d_in, const int* in_sizes, int n_in,
                              void* d_out, int out_size, void* d_ws, size_t ws_size,
                              hipStream_t stream) {
    (void)in_sizes; (void)n_in; (void)out_size; (void)ws_size;
    const float* x    = (const float*)d_in[0];
    const int*   done = (const int*)  d_in[1];
    const float* h0   = (const float*)d_in[2];
    const float* c0   = (const float*)d_in[3];
    const float* w1   = (const float*)d_in[4];
    const float* b1   = (const float*)d_in[5];
    const float* w2   = (const float*)d_in[6];
    const float* b2   = (const float*)d_in[7];
    const float* w3   = (const float*)d_in[8];
    const float* b3   = (const float*)d_in[9];
    const float* fcW  = (const float*)d_in[10];
    const float* fcb  = (const float*)d_in[11];
    const float* Wih  = (const float*)d_in[12];
    const float* Whh  = (const float*)d_in[13];
    const float* bih  = (const float*)d_in[14];
    const float* bhh  = (const float*)d_in[15];
    const float* A1   = (const float*)d_in[16];
    const float* Ab1  = (const float*)d_in[17];
    const float* A2   = (const float*)d_in[18];
    const float* Ab2  = (const float*)d_in[19];
    const float* C1   = (const float*)d_in[20];
    const float* Cb1  = (const float*)d_in[21];
    const float* C2   = (const float*)d_in[22];
    const float* Cb2  = (const float*)d_in[23];
    float* out = (float*)d_out;

    char* wsp = (char*)d_ws;
    auto alloc = [&](size_t bytes) {
        char* p = wsp; wsp += (bytes + 255) & ~(size_t)255; return p;
    };
    short* a1s  = (short*)alloc(18530304ull * 2);  // [512*1131][32]
    short* a2s  = (short*)alloc(7667712ull * 2);   // [512*234][64]
    short* a3s  = (short*)alloc(5767168ull * 2);   // [512*176][64]
    short* hfc  = (short*)alloc(262144ull * 2);    // [512][512]
    float* P    = (float*)alloc(1048576ull * 4);   // [512][2048]
    short* whhb = (short*)alloc(1048576ull * 2);   // Whh bf16 [2048][512]
    u64*   hq0  = (u64*)  alloc(16384ull * 2);     // masked h, qword view
    u64*   hq1  = (u64*)  alloc(16384ull * 2);
    short* nh   = (short*)alloc(262144ull * 2);
    short* aAC  = (short*)alloc(524288ull * 2);    // [512][1024]
    float* part = (float*)alloc(1048576ull * 4);   // FC split-K partials
    short* wc1  = (short*)alloc(6144ull * 2);
    short* wc2  = (short*)alloc(32768ull * 2);
    short* wc3  = (short*)alloc(36864ull * 2);
    short* fcwr = (short*)alloc(5767168ull * 2);
    short* wihb = (short*)alloc(1048576ull * 2);
    short* a1b  = (short*)alloc(262144ull * 2);
    short* c1b  = (short*)alloc(262144ull * 2);
    short* a2b  = (short*)alloc(4096ull * 2);
    short* c2b  = (short*)alloc(512ull * 2);
    float* bias2  = (float*)alloc(2048ull * 4);
    float* biasAC = (float*)alloc(1024ull * 4);
    unsigned* bar = (unsigned*)alloc(256);

    // all prep in one launch
    k_megaprep<<<3432, 256, 0, stream>>>(w1, w2, w3, fcW, Wih, Whh, A1, C1, A2, C2,
                                         h0, done, bih, bhh, Ab1, Cb1,
                                         wc1, wc2, wc3, fcwr, wihb, whhb,
                                         a1b, c1b, a2b, c2b, (short*)hq0,
                                         bias2, biasAC, bar);

    // convs
    k_conv1_v3<<<9048, 256, 0, stream>>>(x, wc1, b1, a1s);
    k_conv2_v2<<<512, 256, 0, stream>>>(a1s, wc2, b2, a2s);
    k_conv3_v2<<<512, 256, 0, stream>>>(a2s, wc3, b3, a3s);

    // FC: split-K 4 + epilogue
    k_gemm_mfma<<<dim3(8, 8, 4), 256, 0, stream>>>(a3s, fcwr, part, 512, 512, 11264, 2816);
    {   // epilogue fused into a tiny pass via k_gemm_bias is not applicable (S=4):
        // reuse dedicated epilogue
    }
    // FC epilogue (sum 4 splits + bias + leaky 0.2 -> bf16)
    // (kept as a lambda-free kernel below)
    extern __global__ void k_epilogue(const float*, const float*, short*, float*, int, int, int, float);
    k_epilogue<<<256, 256, 0, stream>>>(part, fcb, hfc, nullptr, 262144, 512, 4, 0.2f);

    // P = hfc @ Wih^T + (bih + bhh)  (fused epilogue, f32 out)
    k_gemm_bias<<<dim3(32, 8), 256, 0, stream>>>(hfc, wihb, bias2, nullptr, P,
                                                 512, 2048, 512, 1.0f);

    // LSTM: one persistent launch, fence-free barrier
    k_lstm_all2<<<32, 256, 0, stream>>>(P, whhb, done, hq0, hq1, c0, nh,
                                        out + 4608, out + 20992, bar);

    // heads: combined [A1;C1] GEMM (fused epilogue, bf16 out)
    k_gemm_bias<<<dim3(16, 8), 256, 0, stream>>>(nh, a1b, biasAC, aAC, nullptr,
                                                 512, 1024, 512, 0.01f);
    k_heads<<<1152, 256, 0, stream>>>(aAC, a2b, Ab2, c2b, Cb2, out);
}

// FC epilogue: sum splits + bias + leaky -> bf16
__global__ void k_epilogue(const float* __restrict__ part, const float* __restrict__ bias,
                           short* __restrict__ out_b, float* __restrict__ out_f,
                           int MN, int N, int S, float slope) {
    int i = (blockIdx.x * 256 + threadIdx.x) * 4;
    if (i >= MN) return;
    float4 v = *(const float4*)(part + i);
    for (int s = 1; s < S; ++s) {
        float4 p = *(const float4*)(part + (size_t)s * MN + i);
        v.x += p.x; v.y += p.y; v.z += p.z; v.w += p.w;
    }
    float4 b = *(const float4*)(bias + (i % N));
    v.x += b.x; v.y += b.y; v.z += b.z; v.w += b.w;
    v.x = (v.x >= 0.f) ? v.x : v.x * slope;
    v.y = (v.y >= 0.f) ? v.y : v.y * slope;
    v.z = (v.z >= 0.f) ? v.z : v.z * slope;
    v.w = (v.w >= 0.f) ? v.w : v.w * slope;
    if (out_b) {
        out_b[i + 0] = f2bs(v.x); out_b[i + 1] = f2bs(v.y);
        out_b[i + 2] = f2bs(v.z); out_b[i + 3] = f2bs(v.w);
    }
    if (out_f) *(float4*)(out_f + i) = v;
}

// Round 7
// 251.713 us; speedup vs baseline: 1.2117x; 1.1429x over previous
//
#include <hip/hip_runtime.h>
#include <hip/hip_bf16.h>
#include <math.h>

using short8 = __attribute__((ext_vector_type(8))) short;   // 8 bf16 (4 VGPR)
using f32x4  = __attribute__((ext_vector_type(4))) float;   // MFMA acc
typedef unsigned long long u64;

#define MFMA16(a, b, c) __builtin_amdgcn_mfma_f32_16x16x32_bf16(a, b, c, 0, 0, 0)

__device__ __forceinline__ short f2bs(float f) {
    __hip_bfloat16 h = __float2bfloat16(f);          // RNE
    return __builtin_bit_cast(short, h);
}
__device__ __forceinline__ float bs2f(short s) {
    return __uint_as_float(((unsigned)(unsigned short)s) << 16);
}
__device__ __forceinline__ unsigned pk2(float a, float b) {
    return ((unsigned)(unsigned short)f2bs(a)) | (((unsigned)(unsigned short)f2bs(b)) << 16);
}

// ---------------- mega-prep: all weight conversions + transposes in ONE launch ----------------
__global__ void __launch_bounds__(256) k_megaprep(
        const float* __restrict__ w1, const float* __restrict__ w2,
        const float* __restrict__ w3, const float* __restrict__ fcW,
        const float* __restrict__ Wih, const float* __restrict__ Whh,
        const float* __restrict__ A1, const float* __restrict__ C1,
        const float* __restrict__ A2, const float* __restrict__ C2,
        const float* __restrict__ h0, const int* __restrict__ done,
        const float* __restrict__ bih, const float* __restrict__ bhh,
        const float* __restrict__ Ab1, const float* __restrict__ Cb1,
        short* __restrict__ wc1, short* __restrict__ wc2, short* __restrict__ wc3,
        short* __restrict__ fcwr, short* __restrict__ wihb, short* __restrict__ whhb,
        short* __restrict__ a1b, short* __restrict__ c1b, short* __restrict__ a2b,
        short* __restrict__ c2b, short* __restrict__ hm0,
        float* __restrict__ bias2, float* __restrict__ biasAC, unsigned* __restrict__ flags) {
    __shared__ short t[176 * 76];
    const int bid = blockIdx.x, tid = threadIdx.x;

    auto cvt4 = [&](const float* in, short* out, int i) {
        float4 v = *(const float4*)(in + i * 4);
        out[i * 4 + 0] = f2bs(v.x); out[i * 4 + 1] = f2bs(v.y);
        out[i * 4 + 2] = f2bs(v.z); out[i * 4 + 3] = f2bs(v.w);
    };

    if (bid < 512) {
        // fcW [512][11264] (K = oc*176+pix) -> fcwr [512][pix*64+oc]
        int r = bid;
        for (int it = 0; it < 11; ++it) {
            int c4 = it * 256 + tid;
            float4 v = *(const float4*)(fcW + (size_t)r * 11264 + c4 * 4);
            int c = c4 * 4;
            int oc = c / 176, pix = c % 176;
            t[(pix + 0) * 76 + oc] = f2bs(v.x);
            t[(pix + 1) * 76 + oc] = f2bs(v.y);
            t[(pix + 2) * 76 + oc] = f2bs(v.z);
            t[(pix + 3) * 76 + oc] = f2bs(v.w);
        }
        __syncthreads();
        for (int it = 0; it < 6; ++it) {
            int j8 = it * 256 + tid;
            if (j8 < 1408) {
                int j = j8 * 8, pix = j >> 6, oc0 = j & 63;
                const short* tp = &t[pix * 76 + oc0];
                short8 v;
                ((uint2*)&v)[0] = *(const uint2*)tp;
                ((uint2*)&v)[1] = *(const uint2*)(tp + 4);
                *(short8*)&fcwr[(size_t)r * 11264 + j] = v;
            }
        }
    } else if (bid < 1536) {
        cvt4(Wih, wihb, (bid - 512) * 256 + tid);
    } else if (bid < 2560) {
        cvt4(Whh, whhb, (bid - 1536) * 256 + tid);
    } else if (bid < 2816) {
        cvt4(A1, a1b, (bid - 2560) * 256 + tid);
    } else if (bid < 3072) {
        cvt4(C1, c1b, (bid - 2816) * 256 + tid);
    } else if (bid < 3078) {
        cvt4(w1, wc1, (bid - 3072) * 256 + tid);       // layout already (ic*64+kh*8+kw)
    } else if (bid < 3206) {
        int i = (bid - 3078) * 256 + tid;              // 32768
        int oc = i >> 9, col = i & 511;
        int kh = col >> 7, kw = (col >> 5) & 3, ic = col & 31;
        wc2[i] = f2bs(w2[((oc * 32 + ic) * 4 + kh) * 4 + kw]);
    } else if (bid < 3350) {
        int i = (bid - 3206) * 256 + tid;              // 36864
        int oc = i / 576, col = i % 576;
        int kh = col / 192, r = col % 192, kw = r >> 6, ic = r & 63;
        wc3[i] = f2bs(w3[((oc * 64 + ic) * 3 + kh) * 3 + kw]);
    } else if (bid < 3354) {
        cvt4(A2, a2b, (bid - 3350) * 256 + tid);
    } else if (bid < 3355) {
        if (tid < 128) cvt4(C2, c2b, tid);
    } else if (bid < 3419) {
        int i = (bid - 3355) * 256 + tid;              // 16384
        float m = 1.f - (float)done[i >> 9];
        hm0[i] = f2bs(h0[i] * m);
    } else if (bid < 3427) {
        int i = (bid - 3419) * 256 + tid;              // 2048
        bias2[i] = bih[i] + bhh[i];
    } else if (bid < 3431) {
        int i = (bid - 3427) * 256 + tid;              // 1024
        biasAC[i] = (i < 512) ? Ab1[i] : Cb1[i - 512];
    } else {
        if (tid < 16) flags[tid] = 0u;
    }
}

// ---------------- conv1 v3: direct-global MFMA ----------------
__global__ void __launch_bounds__(256) k_conv1_v3(const float* __restrict__ x,
                                                  const short* __restrict__ Wc,
                                                  const float* __restrict__ bias,
                                                  short* __restrict__ y) {
    __shared__ short ct[4][512];        // per-wave [16 px][32 oc]
    const int tid = threadIdx.x;
    const int w = tid >> 6, l = tid & 63;
    const int lr = l & 15, lg = l >> 4;
    const int t = blockIdx.x * 4 + w;   // 0..36191 exact (9048*4)
    short8 bf[6][2];
#pragma unroll
    for (int ks = 0; ks < 6; ++ks)
#pragma unroll
        for (int nf = 0; nf < 2; ++nf)
            bf[ks][nf] = *(const short8*)&Wc[(nf * 16 + lr) * 192 + ks * 32 + lg * 8];
    const float bc0 = bias[lr], bc1 = bias[16 + lr];
    unsigned m = (unsigned)(t * 16 + lr);
    unsigned n = m / 1131u, pix = m % 1131u;
    unsigned oh = pix / 39u, ow = pix - oh * 39u;
    const float* base = x + (size_t)n * 57600 + (oh * 4) * 160 + ow * 4;
    float4 f[6][2];
#pragma unroll
    for (int ks = 0; ks < 6; ++ks) {
        int ic = ks >> 1, kh = (ks & 1) * 4 + lg;
        const float* ap = base + ic * 19200 + kh * 160;
        f[ks][0] = *(const float4*)ap;
        f[ks][1] = *(const float4*)(ap + 4);
    }
    f32x4 acc[2] = {};
#pragma unroll
    for (int ks = 0; ks < 6; ++ks) {
        short8 a;
        a[0] = f2bs(f[ks][0].x); a[1] = f2bs(f[ks][0].y);
        a[2] = f2bs(f[ks][0].z); a[3] = f2bs(f[ks][0].w);
        a[4] = f2bs(f[ks][1].x); a[5] = f2bs(f[ks][1].y);
        a[6] = f2bs(f[ks][1].z); a[7] = f2bs(f[ks][1].w);
        acc[0] = MFMA16(a, bf[ks][0], acc[0]);
        acc[1] = MFMA16(a, bf[ks][1], acc[1]);
    }
#pragma unroll
    for (int j = 0; j < 4; ++j) {
        ct[w][(lg * 4 + j) * 32 + lr] = f2bs(fmaxf(acc[0][j] + bc0, 0.f));
        ct[w][(lg * 4 + j) * 32 + 16 + lr] = f2bs(fmaxf(acc[1][j] + bc1, 0.f));
    }
    int row = l >> 2, c8 = (l & 3) * 8;
    short8 v = *(const short8*)&ct[w][row * 32 + c8];
    *(short8*)&y[((size_t)t * 16 + row) * 32 + c8] = v;
}

// ---------------- conv2: a1 NHWC -> a2 NHWC [n][234 px][64] ----------------
__global__ void __launch_bounds__(256, 2) k_conv2_v2(const short* __restrict__ a1,
                                                     const short* __restrict__ Wc,
                                                     const float* __restrict__ bias,
                                                     short* __restrict__ y) {
    __shared__ short img[36192];        // [29][39][32] swizzled
    __shared__ short ct[2][1024];
    const int n = blockIdx.x, tid = threadIdx.x;
    const int w = tid >> 6, l = tid & 63, lr = l & 15, lg = l >> 4;
    const int par = w >> 1, nfh = w & 1;
    short8 bfg[16][2];
#pragma unroll
    for (int ks = 0; ks < 16; ++ks)
#pragma unroll
        for (int q2 = 0; q2 < 2; ++q2)
            bfg[ks][q2] = *(const short8*)&Wc[(nfh * 32 + q2 * 16 + lr) * 512 + ks * 32 + lg * 8];
    float bc[2] = {bias[nfh * 32 + lr], bias[nfh * 32 + 16 + lr]};
    const short* src = a1 + (size_t)n * 36192;
    for (int it = 0; it < 18; ++it) {
        int i8 = it * 256 + tid;
        if (i8 < 4524) {
            short8 v = *(const short8*)(src + i8 * 8);
            int b = i8 * 16;
            b ^= ((b >> 7) & 7) << 4;
            *(short8*)((char*)img + b) = v;
        }
    }
    __syncthreads();
    for (int t = par; t < 16; t += 2) {
        int p = t * 16 + lr;
        int pc = p < 234 ? p : 233;
        int oh = pc / 18, ow = pc - oh * 18;
        int base = (oh * 2 * 39 + ow * 2) * 64 + lg * 16;
        f32x4 acc[2] = {};
#pragma unroll
        for (int ks = 0; ks < 16; ++ks) {
            int kh = ks >> 2, kw = ks & 3;
            int b = base + (kh * 39 + kw) * 64;
            b ^= ((b >> 7) & 7) << 4;
            short8 a = *(const short8*)((const char*)img + b);
            acc[0] = MFMA16(a, bfg[ks][0], acc[0]);
            acc[1] = MFMA16(a, bfg[ks][1], acc[1]);
        }
#pragma unroll
        for (int q2 = 0; q2 < 2; ++q2)
#pragma unroll
            for (int j = 0; j < 4; ++j)
                ct[par][(lg * 4 + j) * 64 + nfh * 32 + q2 * 16 + lr] =
                    f2bs(fmaxf(acc[q2][j] + bc[q2], 0.f));
        __syncthreads();
        int li = nfh * 64 + l;
        int row = li >> 3, c8 = (li & 7) * 8;
        short8 v = *(const short8*)&ct[par][row * 64 + c8];
        int pg = t * 16 + row;
        if (pg < 234)
            *(short8*)&y[((size_t)n * 234 + pg) * 64 + c8] = v;
        __syncthreads();
    }
}

// ---------------- conv3: a2 NHWC -> a3 NHWC [n][176 px][64] ----------------
__global__ void __launch_bounds__(256, 2) k_conv3_v2(const short* __restrict__ a2,
                                                     const short* __restrict__ Wc,
                                                     const float* __restrict__ bias,
                                                     short* __restrict__ y) {
    __shared__ short img[14976];        // [13][18][64] swizzled
    __shared__ short ct[2][1024];
    const int n = blockIdx.x, tid = threadIdx.x;
    const int w = tid >> 6, l = tid & 63, lr = l & 15, lg = l >> 4;
    const int par = w >> 1, nfh = w & 1;
    short8 bfg[18][2];
#pragma unroll
    for (int ks = 0; ks < 18; ++ks)
#pragma unroll
        for (int q2 = 0; q2 < 2; ++q2)
            bfg[ks][q2] = *(const short8*)&Wc[(nfh * 32 + q2 * 16 + lr) * 576 + ks * 32 + lg * 8];
    float bc[2] = {bias[nfh * 32 + lr], bias[nfh * 32 + 16 + lr]};
    const short* src = a2 + (size_t)n * 14976;
    for (int it = 0; it < 8; ++it) {
        int i8 = it * 256 + tid;
        if (i8 < 1872) {
            short8 v = *(const short8*)(src + i8 * 8);
            int b = i8 * 16;
            b ^= ((b >> 7) & 7) << 4;
            *(short8*)((char*)img + b) = v;
        }
    }
    __syncthreads();
    for (int t = par; t < 12; t += 2) {
        int p = t * 16 + lr;
        int pc = p < 176 ? p : 175;
        int oh = pc >> 4, ow = pc & 15;
        int base = (oh * 18 + ow) * 128 + lg * 16;
        f32x4 acc[2] = {};
#pragma unroll
        for (int ks = 0; ks < 18; ++ks) {
            int kh = ks / 6, r6 = ks % 6, kw = r6 >> 1, ich = r6 & 1;
            int b = base + (kh * 18 + kw) * 128 + ich * 64;
            b ^= ((b >> 7) & 7) << 4;
            short8 a = *(const short8*)((const char*)img + b);
            acc[0] = MFMA16(a, bfg[ks][0], acc[0]);
            acc[1] = MFMA16(a, bfg[ks][1], acc[1]);
        }
#pragma unroll
        for (int q2 = 0; q2 < 2; ++q2)
#pragma unroll
            for (int j = 0; j < 4; ++j)
                ct[par][(lg * 4 + j) * 64 + nfh * 32 + q2 * 16 + lr] =
                    f2bs(fmaxf(acc[q2][j] + bc[q2], 0.f));
        __syncthreads();
        int li = nfh * 64 + l;
        int row = li >> 3, c8 = (li & 7) * 8;
        short8 v = *(const short8*)&ct[par][row * 64 + c8];
        int pg = t * 16 + row;
        if (pg < 176)
            *(short8*)&y[((size_t)n * 176 + pg) * 64 + c8] = v;
        __syncthreads();
    }
}

// ---------------- MFMA GEMM core: part[z][M][N] = A @ W^T (split-K, FC only) ----------------
__global__ void k_gemm_mfma(const short* __restrict__ A, const short* __restrict__ W,
                            float* __restrict__ part, int M, int N, int K, int kPerSplit) {
    __shared__ short As[64 * 40];
    __shared__ short Ws[64 * 40];
    const int tid = threadIdx.x;
    const int m0 = blockIdx.y * 64, n0 = blockIdx.x * 64;
    const int k0s = blockIdx.z * kPerSplit, k0e = k0s + kPerSplit;
    const int w = tid >> 6, l = tid & 63;
    const int wr = w >> 1, wc = w & 1;
    const int sr = tid >> 2, sc = tid & 3;
    const int lr = l & 15, lg = l >> 4;
    f32x4 acc[2][2] = {};
    for (int k0 = k0s; k0 < k0e; k0 += 32) {
        short8 av = *(const short8*)(A + (size_t)(m0 + sr) * K + k0 + sc * 8);
        short8 wv = *(const short8*)(W + (size_t)(n0 + sr) * K + k0 + sc * 8);
        __syncthreads();
        *(short8*)&As[sr * 40 + sc * 8] = av;
        *(short8*)&Ws[sr * 40 + sc * 8] = wv;
        __syncthreads();
        int cb = lg * 8;
        short8 a0 = *(const short8*)&As[(wr * 32 + lr) * 40 + cb];
        short8 a1 = *(const short8*)&As[(wr * 32 + 16 + lr) * 40 + cb];
        short8 b0 = *(const short8*)&Ws[(wc * 32 + lr) * 40 + cb];
        short8 b1 = *(const short8*)&Ws[(wc * 32 + 16 + lr) * 40 + cb];
        acc[0][0] = MFMA16(a0, b0, acc[0][0]);
        acc[0][1] = MFMA16(a0, b1, acc[0][1]);
        acc[1][0] = MFMA16(a1, b0, acc[1][0]);
        acc[1][1] = MFMA16(a1, b1, acc[1][1]);
    }
    float* pp = part + (size_t)blockIdx.z * M * N;
#pragma unroll
    for (int mi = 0; mi < 2; ++mi)
#pragma unroll
        for (int ni = 0; ni < 2; ++ni)
#pragma unroll
            for (int j = 0; j < 4; ++j) {
                int row = m0 + wr * 32 + mi * 16 + lg * 4 + j;
                int col = n0 + wc * 32 + ni * 16 + lr;
                pp[(size_t)row * N + col] = acc[mi][ni][j];
            }
}

// FC epilogue: sum splits + bias + leaky -> bf16/f32
__global__ void k_epilogue(const float* __restrict__ part, const float* __restrict__ bias,
                           short* __restrict__ out_b, float* __restrict__ out_f,
                           int MN, int N, int S, float slope) {
    int i = (blockIdx.x * 256 + threadIdx.x) * 4;
    if (i >= MN) return;
    float4 v = *(const float4*)(part + i);
    for (int s = 1; s < S; ++s) {
        float4 p = *(const float4*)(part + (size_t)s * MN + i);
        v.x += p.x; v.y += p.y; v.z += p.z; v.w += p.w;
    }
    float4 b = *(const float4*)(bias + (i % N));
    v.x += b.x; v.y += b.y; v.z += b.z; v.w += b.w;
    v.x = (v.x >= 0.f) ? v.x : v.x * slope;
    v.y = (v.y >= 0.f) ? v.y : v.y * slope;
    v.z = (v.z >= 0.f) ? v.z : v.z * slope;
    v.w = (v.w >= 0.f) ? v.w : v.w * slope;
    if (out_b) {
        out_b[i + 0] = f2bs(v.x); out_b[i + 1] = f2bs(v.y);
        out_b[i + 2] = f2bs(v.z); out_b[i + 3] = f2bs(v.w);
    }
    if (out_f) *(float4*)(out_f + i) = v;
}

// ---------------- GEMM with fused bias+leaky epilogue (S=1 cases) ----------------
__global__ void k_gemm_bias(const short* __restrict__ A, const short* __restrict__ W,
                            const float* __restrict__ bias, short* __restrict__ out_b,
                            float* __restrict__ out_f, int M, int N, int K, float slope) {
    __shared__ short As[64 * 40];
    __shared__ short Ws[64 * 40];
    const int tid = threadIdx.x;
    const int m0 = blockIdx.y * 64, n0 = blockIdx.x * 64;
    const int w = tid >> 6, l = tid & 63;
    const int wr = w >> 1, wc = w & 1;
    const int sr = tid >> 2, sc = tid & 3;
    const int lr = l & 15, lg = l >> 4;
    f32x4 acc[2][2] = {};
    for (int k0 = 0; k0 < K; k0 += 32) {
        short8 av = *(const short8*)(A + (size_t)(m0 + sr) * K + k0 + sc * 8);
        short8 wv = *(const short8*)(W + (size_t)(n0 + sr) * K + k0 + sc * 8);
        __syncthreads();
        *(short8*)&As[sr * 40 + sc * 8] = av;
        *(short8*)&Ws[sr * 40 + sc * 8] = wv;
        __syncthreads();
        int cb = lg * 8;
        short8 a0 = *(const short8*)&As[(wr * 32 + lr) * 40 + cb];
        short8 a1 = *(const short8*)&As[(wr * 32 + 16 + lr) * 40 + cb];
        short8 b0 = *(const short8*)&Ws[(wc * 32 + lr) * 40 + cb];
        short8 b1 = *(const short8*)&Ws[(wc * 32 + 16 + lr) * 40 + cb];
        acc[0][0] = MFMA16(a0, b0, acc[0][0]);
        acc[0][1] = MFMA16(a0, b1, acc[0][1]);
        acc[1][0] = MFMA16(a1, b0, acc[1][0]);
        acc[1][1] = MFMA16(a1, b1, acc[1][1]);
    }
#pragma unroll
    for (int mi = 0; mi < 2; ++mi)
#pragma unroll
        for (int ni = 0; ni < 2; ++ni)
#pragma unroll
            for (int j = 0; j < 4; ++j) {
                int row = m0 + wr * 32 + mi * 16 + lg * 4 + j;
                int col = n0 + wc * 32 + ni * 16 + lr;
                float v = acc[mi][ni][j] + bias[col];
                v = (v >= 0.f) ? v : v * slope;
                if (out_f) out_f[(size_t)row * N + col] = v;
                else       out_b[(size_t)row * N + col] = f2bs(v);
            }
}

// ---------------- persistent LSTM v3: 16 blocks x 1024 threads ----------------
// Block b owns 32 hidden units (128 gate rows). Weights in VGPRs. h exchange via
// coherent (sc0sc1) atomics: 4 u64 loads/thread/step, 16 waves hide latency.
__global__ void __launch_bounds__(1024) k_lstm_all3(
        const float* __restrict__ P, const short* __restrict__ Whhb,
        const int* __restrict__ done, u64* __restrict__ hq0, u64* __restrict__ hq1,
        const float* __restrict__ c0, short* __restrict__ nh,
        float* __restrict__ outH, float* __restrict__ outC, unsigned* __restrict__ flags) {
    __shared__ short hs[32 * 520];      // h staging [32 batch][512+8]
    __shared__ float gb[4 * 32 * 33];   // gates [gate][unit_local][batch] padded
    __shared__ short ch[32 * 33];       // h-chunk [unit_local][batch] padded
    const int b = blockIdx.x;
    const int tid = threadIdx.x;
    const int w = tid >> 6, l = tid & 63, lr = l & 15, lg = l >> 4;
    const int mt = w & 1, nt = w >> 1;           // wave -> (batch-half, gate-row-16)
    const int r = nt * 16 + lr;                  // gate-local row 0..127
    const int gate = r >> 5, ul = r & 31;
    const int G = gate * 512 + b * 32 + ul;      // global gate row
    // weights for this lane's gate row: 16 x short8 = 64 VGPR (plain loads, L2)
    short8 bfg[16];
    const short* wrow = Whhb + (size_t)G * 512;
#pragma unroll
    for (int ks = 0; ks < 16; ++ks) bfg[ks] = *(const short8*)(wrow + ks * 32 + lg * 8);
    // c-state cell: (cu = tid>>5 unit_local, cb = tid&31 batch)
    const int cu = tid >> 5, cb = tid & 31;
    float cr = c0[cb * 512 + b * 32 + cu];

    for (int t = 0; t < 16; ++t) {
        const u64* hin = (t & 1) ? hq1 : hq0;
        u64* hout      = (t & 1) ? hq0 : hq1;
        // stage h: 4096 u64 over 1024 threads = 4 each (coherent loads)
#pragma unroll
        for (int it = 0; it < 4; ++it) {
            int i = it * 1024 + tid;
            u64 g = __hip_atomic_load(hin + i, __ATOMIC_RELAXED, __HIP_MEMORY_SCOPE_AGENT);
            *(u64*)&hs[(i >> 7) * 520 + (i & 127) * 4] = g;
        }
        __syncthreads();
        f32x4 acc = {};
#pragma unroll
        for (int ks = 0; ks < 16; ++ks) {
            short8 a = *(const short8*)&hs[(mt * 16 + lr) * 520 + ks * 32 + lg * 8];
            acc = MFMA16(a, bfg[ks], acc);
        }
        // D: col=lr -> gate row r; row = batch mt*16 + lg*4 + j. Add P, stash in gb.
#pragma unroll
        for (int j = 0; j < 4; ++j) {
            int batch = mt * 16 + lg * 4 + j;
            gb[gate * 1056 + ul * 33 + batch] =
                acc[j] + P[(size_t)(t * 32 + batch) * 2048 + G];
        }
        __syncthreads();
        // pointwise: one cell per thread
        {
            float gi = gb[0 * 1056 + cu * 33 + cb];
            float gf = gb[1 * 1056 + cu * 33 + cb];
            float gg = gb[2 * 1056 + cu * 33 + cb];
            float go = gb[3 * 1056 + cu * 33 + cb];
            float m = 1.f - (float)done[t * 32 + cb];
            float ig = 1.f / (1.f + expf(-gi));
            float fg = 1.f / (1.f + expf(-gf));
            float gt = tanhf(gg);
            float og = 1.f / (1.f + expf(-go));
            float cn = fg * (cr * m) + ig * gt;
            float hn = og * tanhf(cn);
            cr = cn;
            ch[cu * 33 + cb] = f2bs(hn);
            if (t == 15) {
                outH[cb * 512 + b * 32 + cu] = hn;
                outC[cb * 512 + b * 32 + cu] = cn;
            }
        }
        __syncthreads();
        // nh write (coalesced via ch): 512 threads x 2 units
        if (tid < 512) {
            int bb2 = tid >> 4, up = (tid & 15) * 2;
            unsigned pkv = ((unsigned)(unsigned short)ch[up * 33 + bb2]) |
                           (((unsigned)(unsigned short)ch[(up + 1) * 33 + bb2]) << 16);
            *(unsigned*)&nh[(size_t)(t * 32 + bb2) * 512 + b * 32 + up] = pkv;
        }
        if (t < 15) {
            // hout chunk: 256 threads x 4 units, masked by done[t+1], coherent stores
            if (tid < 256) {
                int bb3 = tid >> 3, uq = (tid & 7) * 4;
                u64 q = 0;
                if (!done[(t + 1) * 32 + bb3]) {
                    unsigned lo = ((unsigned)(unsigned short)ch[uq * 33 + bb3]) |
                                  (((unsigned)(unsigned short)ch[(uq + 1) * 33 + bb3]) << 16);
                    unsigned hi = ((unsigned)(unsigned short)ch[(uq + 2) * 33 + bb3]) |
                                  (((unsigned)(unsigned short)ch[(uq + 3) * 33 + bb3]) << 16);
                    q = (u64)lo | ((u64)hi << 32);
                }
                __hip_atomic_store(hout + bb3 * 128 + b * 8 + (tid & 7), q,
                                   __ATOMIC_RELAXED, __HIP_MEMORY_SCOPE_AGENT);
            }
            asm volatile("s_waitcnt vmcnt(0)" ::: "memory");
            __syncthreads();                   // all waves' stores at coherent point
            if (tid == 0)
                __hip_atomic_store(flags + b, (unsigned)(t + 1),
                                   __ATOMIC_RELAXED, __HIP_MEMORY_SCOPE_AGENT);
            if (tid < 16) {
                while (__hip_atomic_load(flags + tid, __ATOMIC_RELAXED,
                                         __HIP_MEMORY_SCOPE_AGENT) < (unsigned)(t + 1))
                    __builtin_amdgcn_s_sleep(1);
            }
            __syncthreads();
        }
    }
}

// ---------------- small heads: logits [512][8] + value [512] ----------------
__global__ void k_heads(const short* __restrict__ aAC,
                        const short* __restrict__ A2b, const float* __restrict__ Ab2,
                        const short* __restrict__ C2b, const float* __restrict__ Cb2,
                        float* __restrict__ out) {
    int idx = blockIdx.x * 4 + (threadIdx.x >> 6);
    int l = threadIdx.x & 63;
    if (idx >= 4608) return;
    int row = idx / 9, col = idx % 9;
    const short* act = aAC + (size_t)row * 1024 + (col < 8 ? 0 : 512);
    const short* wr  = (col < 8) ? (A2b + (size_t)col * 512) : C2b;
    short8 a = *(const short8*)(act + l * 8);
    short8 wv = *(const short8*)(wr + l * 8);
    float s = 0.f;
#pragma unroll
    for (int q = 0; q < 8; ++q) s += bs2f(a[q]) * bs2f(wv[q]);
#pragma unroll
    for (int off = 32; off > 0; off >>= 1) s += __shfl_xor(s, off, 64);
    if (l == 0) {
        if (col < 8) out[row * 8 + col] = s + Ab2[col];
        else out[4096 + row] = s + Cb2[0];
    }
}

// ---------------- launch ----------------

extern "C" void kernel_launch(void* const* d_in, const int* in_sizes, int n_in,
                              void* d_out, int out_size, void* d_ws, size_t ws_size,
                              hipStream_t stream) {
    (void)in_sizes; (void)n_in; (void)out_size; (void)ws_size;
    const float* x    = (const float*)d_in[0];
    const int*   done = (const int*)  d_in[1];
    const float* h0   = (const float*)d_in[2];
    const float* c0   = (const float*)d_in[3];
    const float* w1   = (const float*)d_in[4];
    const float* b1   = (const float*)d_in[5];
    const float* w2   = (const float*)d_in[6];
    const float* b2   = (const float*)d_in[7];
    const float* w3   = (const float*)d_in[8];
    const float* b3   = (const float*)d_in[9];
    const float* fcW  = (const float*)d_in[10];
    const float* fcb  = (const float*)d_in[11];
    const float* Wih  = (const float*)d_in[12];
    const float* Whh  = (const float*)d_in[13];
    const float* bih  = (const float*)d_in[14];
    const float* bhh  = (const float*)d_in[15];
    const float* A1   = (const float*)d_in[16];
    const float* Ab1  = (const float*)d_in[17];
    const float* A2   = (const float*)d_in[18];
    const float* Ab2  = (const float*)d_in[19];
    const float* C1   = (const float*)d_in[20];
    const float* Cb1  = (const float*)d_in[21];
    const float* C2   = (const float*)d_in[22];
    const float* Cb2  = (const float*)d_in[23];
    float* out = (float*)d_out;

    char* wsp = (char*)d_ws;
    auto alloc = [&](size_t bytes) {
        char* p = wsp; wsp += (bytes + 255) & ~(size_t)255; return p;
    };
    short* a1s  = (short*)alloc(18530304ull * 2);  // [512*1131][32]
    short* a2s  = (short*)alloc(7667712ull * 2);   // [512*234][64]
    short* a3s  = (short*)alloc(5767168ull * 2);   // [512*176][64]
    short* hfc  = (short*)alloc(262144ull * 2);    // [512][512]
    float* P    = (float*)alloc(1048576ull * 4);   // [512][2048]
    short* whhb = (short*)alloc(1048576ull * 2);   // Whh bf16 [2048][512]
    u64*   hq0  = (u64*)  alloc(16384ull * 2);     // masked h, qword view
    u64*   hq1  = (u64*)  alloc(16384ull * 2);
    short* nh   = (short*)alloc(262144ull * 2);
    short* aAC  = (short*)alloc(524288ull * 2);    // [512][1024]
    float* part = (float*)alloc(1048576ull * 4);   // FC split-K partials
    short* wc1  = (short*)alloc(6144ull * 2);
    short* wc2  = (short*)alloc(32768ull * 2);
    short* wc3  = (short*)alloc(36864ull * 2);
    short* fcwr = (short*)alloc(5767168ull * 2);
    short* wihb = (short*)alloc(1048576ull * 2);
    short* a1b  = (short*)alloc(262144ull * 2);
    short* c1b  = (short*)alloc(262144ull * 2);
    short* a2b  = (short*)alloc(4096ull * 2);
    short* c2b  = (short*)alloc(512ull * 2);
    float* bias2  = (float*)alloc(2048ull * 4);
    float* biasAC = (float*)alloc(1024ull * 4);
    unsigned* flags = (unsigned*)alloc(256);

    // all prep in one launch
    k_megaprep<<<3432, 256, 0, stream>>>(w1, w2, w3, fcW, Wih, Whh, A1, C1, A2, C2,
                                         h0, done, bih, bhh, Ab1, Cb1,
                                         wc1, wc2, wc3, fcwr, wihb, whhb,
                                         a1b, c1b, a2b, c2b, (short*)hq0,
                                         bias2, biasAC, flags);

    // convs
    k_conv1_v3<<<9048, 256, 0, stream>>>(x, wc1, b1, a1s);
    k_conv2_v2<<<512, 256, 0, stream>>>(a1s, wc2, b2, a2s);
    k_conv3_v2<<<512, 256, 0, stream>>>(a2s, wc3, b3, a3s);

    // FC: split-K 4 + epilogue
    k_gemm_mfma<<<dim3(8, 8, 4), 256, 0, stream>>>(a3s, fcwr, part, 512, 512, 11264, 2816);
    k_epilogue<<<256, 256, 0, stream>>>(part, fcb, hfc, nullptr, 262144, 512, 4, 0.2f);

    // P = hfc @ Wih^T + (bih + bhh)  (fused epilogue, f32 out)
    k_gemm_bias<<<dim3(32, 8), 256, 0, stream>>>(hfc, wihb, bias2, nullptr, P,
                                                 512, 2048, 512, 1.0f);

    // LSTM: one persistent launch, 16 blocks x 1024 threads
    k_lstm_all3<<<16, 1024, 0, stream>>>(P, whhb, done, hq0, hq1, c0, nh,
                                         out + 4608, out + 20992, flags);

    // heads: combined [A1;C1] GEMM (fused epilogue, bf16 out)
    k_gemm_bias<<<dim3(16, 8), 256, 0, stream>>>(nh, a1b, biasAC, aAC, nullptr,
                                                 512, 1024, 512, 0.01f);
    k_heads<<<1152, 256, 0, stream>>>(aAC, a2b, Ab2, c2b, Cb2, out);
}